// Round 1
// baseline (5947.890 us; speedup 1.0000x reference)
//
#include <hip/hip_runtime.h>

#define CDIV(a,b) (((a)+(b)-1)/(b))

// ---------------- degree / dinv ----------------
__global__ __launch_bounds__(256) void hg_deg_count(const int* __restrict__ dst, int* __restrict__ deg, int E){
    int e = blockIdx.x*256 + threadIdx.x;
    if (e < E) atomicAdd(&deg[dst[e]], 1);
}

__global__ __launch_bounds__(256) void hg_dinv(const int* __restrict__ deg, float* __restrict__ dinv, int N){
    int v = blockIdx.x*256 + threadIdx.x;
    if (v < N) dinv[v] = rsqrtf((float)(deg[v] + 1));   // +1 self-loop; always > 0
}

// ---------------- fused GEMM: G[v][j] = (X[v,:] @ W[:,j]) * dinv[v] ----------------
// block = 256 threads = 4 waves; each wave handles 4 rows, lane = output col (64 cols)
template<int K>
__global__ __launch_bounds__(256) void hg_gemm_scaled(const float* __restrict__ X, const float* __restrict__ W,
                                                      const float* __restrict__ dinv, float* __restrict__ G, int N){
    __shared__ float Wl[K*64];
    for (int i = threadIdx.x; i < K*16; i += 256)
        ((float4*)Wl)[i] = ((const float4*)W)[i];
    __syncthreads();
    const int col  = threadIdx.x & 63;
    const int grp  = threadIdx.x >> 6;      // wave id 0..3
    const int row0 = blockIdx.x * 16 + grp * 4;
    if (row0 >= N) return;
    float a0=0.f, a1=0.f, a2=0.f, a3=0.f;
    const float* x0 = X + (size_t)row0 * K;
    if (row0 + 3 < N) {
        #pragma unroll 4
        for (int k = 0; k < K; k += 4) {
            const float4 xa = *(const float4*)(x0 + 0*(size_t)K + k);
            const float4 xb = *(const float4*)(x0 + 1*(size_t)K + k);
            const float4 xc = *(const float4*)(x0 + 2*(size_t)K + k);
            const float4 xd = *(const float4*)(x0 + 3*(size_t)K + k);
            const float w0 = Wl[(k+0)*64 + col];
            const float w1 = Wl[(k+1)*64 + col];
            const float w2 = Wl[(k+2)*64 + col];
            const float w3 = Wl[(k+3)*64 + col];
            a0 = fmaf(xa.w,w3, fmaf(xa.z,w2, fmaf(xa.y,w1, fmaf(xa.x,w0, a0))));
            a1 = fmaf(xb.w,w3, fmaf(xb.z,w2, fmaf(xb.y,w1, fmaf(xb.x,w0, a1))));
            a2 = fmaf(xc.w,w3, fmaf(xc.z,w2, fmaf(xc.y,w1, fmaf(xc.x,w0, a2))));
            a3 = fmaf(xd.w,w3, fmaf(xd.z,w2, fmaf(xd.y,w1, fmaf(xd.x,w0, a3))));
        }
        G[(size_t)(row0+0)*64 + col] = a0 * dinv[row0+0];
        G[(size_t)(row0+1)*64 + col] = a1 * dinv[row0+1];
        G[(size_t)(row0+2)*64 + col] = a2 * dinv[row0+2];
        G[(size_t)(row0+3)*64 + col] = a3 * dinv[row0+3];
    } else {
        for (int r = 0; r < 4; ++r) {
            int row = row0 + r;
            if (row >= N) break;
            float acc = 0.f;
            const float* xr = X + (size_t)row * K;
            for (int k = 0; k < K; ++k) acc = fmaf(xr[k], Wl[k*64 + col], acc);
            G[(size_t)row*64 + col] = acc * dinv[row];
        }
    }
}

// ---------------- edge scatter: acc[dst] += g[src]  (fp32 atomics) ----------------
// thread handles one (edge, 4-float chunk); 16 consecutive threads cover one edge's 64 feats
__global__ __launch_bounds__(256) void hg_scatter(const float* __restrict__ g, const int* __restrict__ src,
                                                  const int* __restrict__ dst, float* __restrict__ acc, int E){
    long i = (long)blockIdx.x*256 + threadIdx.x;
    if (i >= (long)E*16) return;
    const int e = (int)(i >> 4);
    const int c = ((int)i & 15) << 2;
    const int s = src[e], d = dst[e];
    const float4 v = *(const float4*)(g + (size_t)s*64 + c);
    float* a = acc + (size_t)d*64 + c;
    atomicAdd(a+0, v.x); atomicAdd(a+1, v.y); atomicAdd(a+2, v.z); atomicAdd(a+3, v.w);
}

// ---------------- pointwise: out = relu((acc + g) * dinv[v] + b[col]) ----------------
__global__ __launch_bounds__(256) void hg_pointwise(const float* __restrict__ acc, const float* __restrict__ g,
                                                    const float* __restrict__ dinv, const float* __restrict__ b,
                                                    float* __restrict__ outp, int N){
    long i = (long)blockIdx.x*256 + threadIdx.x;
    if (i >= (long)N*16) return;
    const int v = (int)(i >> 4);
    const int c = ((int)i & 15) << 2;
    const float dv = dinv[v];
    const float4 a  = *(const float4*)(acc + (size_t)v*64 + c);
    const float4 gg = *(const float4*)(g   + (size_t)v*64 + c);
    const float4 bb = *(const float4*)(b + c);
    float4 r;
    r.x = fmaxf(fmaf(a.x+gg.x, dv, bb.x), 0.f);
    r.y = fmaxf(fmaf(a.y+gg.y, dv, bb.y), 0.f);
    r.z = fmaxf(fmaf(a.z+gg.z, dv, bb.z), 0.f);
    r.w = fmaxf(fmaf(a.w+gg.w, dv, bb.w), 0.f);
    *(float4*)(outp + (size_t)v*64 + c) = r;
}

// ---------------- head: out[v][0:2] = H[v,:] @ Wl + bl ----------------
__global__ __launch_bounds__(256) void hg_head(const float* __restrict__ H, const float* __restrict__ Wl,
                                               const float* __restrict__ bl, float* __restrict__ outp, int N){
    int v = blockIdx.x*256 + threadIdx.x;
    if (v >= N) return;
    const float* h = H + (size_t)v*64;
    float a0 = bl[0], a1 = bl[1];
    #pragma unroll
    for (int k4 = 0; k4 < 16; ++k4) {
        const float4 x = *(const float4*)(h + k4*4);
        const float4 wA = *(const float4*)(Wl + k4*8 + 0);   // W[4k..4k+1][0:2]
        const float4 wB = *(const float4*)(Wl + k4*8 + 4);   // W[4k+2..4k+3][0:2]
        a0 = fmaf(x.x, wA.x, a0); a1 = fmaf(x.x, wA.y, a1);
        a0 = fmaf(x.y, wA.z, a0); a1 = fmaf(x.y, wA.w, a1);
        a0 = fmaf(x.z, wB.x, a0); a1 = fmaf(x.z, wB.y, a1);
        a0 = fmaf(x.w, wB.z, a0); a1 = fmaf(x.w, wB.w, a1);
    }
    float2 r; r.x = a0; r.y = a1;
    *(float2*)(outp + (size_t)v*2) = r;
}

// ---------------- orchestration ----------------
static void run_type(const float* x, const int* ei, int E,
                     const float* W1, const float* b1,
                     const float* W2, const float* b2,
                     const float* Wl, const float* bl,
                     float* out, int N,
                     float* bufA, float* bufB, int* deg, float* dinv,
                     hipStream_t stream){
    const int* src = ei;
    const int* dst = ei + E;
    const size_t NB = (size_t)N * 64 * sizeof(float);

    hipMemsetAsync(deg, 0, (size_t)N * sizeof(int), stream);
    hg_deg_count<<<CDIV(E,256), 256, 0, stream>>>(dst, deg, E);
    hg_dinv<<<CDIV(N,256), 256, 0, stream>>>(deg, dinv, N);

    // layer 1
    hg_gemm_scaled<128><<<CDIV(N,16), 256, 0, stream>>>(x, W1, dinv, bufA, N);
    hipMemsetAsync(bufB, 0, NB, stream);
    hg_scatter<<<CDIV((long)E*16, 256), 256, 0, stream>>>(bufA, src, dst, bufB, E);
    hg_pointwise<<<CDIV((long)N*16, 256), 256, 0, stream>>>(bufB, bufA, dinv, b1, bufA, N);

    // layer 2
    hg_gemm_scaled<64><<<CDIV(N,16), 256, 0, stream>>>(bufA, W2, dinv, bufB, N);
    hipMemsetAsync(bufA, 0, NB, stream);   // stream-ordered: runs after gemm finished reading bufA
    hg_scatter<<<CDIV((long)E*16, 256), 256, 0, stream>>>(bufB, src, dst, bufA, E);
    hg_pointwise<<<CDIV((long)N*16, 256), 256, 0, stream>>>(bufA, bufB, dinv, b2, bufB, N);

    // head
    hg_head<<<CDIV(N,256), 256, 0, stream>>>(bufB, Wl, bl, out, N);
}

extern "C" void kernel_launch(void* const* d_in, const int* in_sizes, int n_in,
                              void* d_out, int out_size, void* d_ws, size_t ws_size,
                              hipStream_t stream) {
    const float* x_user = (const float*)d_in[0];
    const float* x_item = (const float*)d_in[1];
    const int*  ei_user = (const int*)d_in[2];
    const int*  ei_item = (const int*)d_in[3];
    const float* W1_user = (const float*)d_in[4];
    const float* b1_user = (const float*)d_in[5];
    const float* W1_item = (const float*)d_in[6];
    const float* b1_item = (const float*)d_in[7];
    const float* W2_user = (const float*)d_in[8];
    const float* b2_user = (const float*)d_in[9];
    const float* W2_item = (const float*)d_in[10];
    const float* b2_item = (const float*)d_in[11];
    const float* Wl_user = (const float*)d_in[12];
    const float* bl_user = (const float*)d_in[13];
    const float* Wl_item = (const float*)d_in[14];
    const float* bl_item = (const float*)d_in[15];

    const int N_user = in_sizes[0] / 128;
    const int N_item = in_sizes[1] / 128;
    const int E_user = in_sizes[2] / 2;
    const int E_item = in_sizes[3] / 2;
    const int NMAX = (N_user > N_item) ? N_user : N_item;

    char* w = (char*)d_ws;
    float* bufA = (float*)w;  w += (size_t)NMAX * 64 * sizeof(float);
    float* bufB = (float*)w;  w += (size_t)NMAX * 64 * sizeof(float);
    int*   deg  = (int*)w;    w += (size_t)NMAX * sizeof(int);
    float* dinv = (float*)w;  w += (size_t)NMAX * sizeof(float);

    float* out = (float*)d_out;

    run_type(x_user, ei_user, E_user, W1_user, b1_user, W2_user, b2_user, Wl_user, bl_user,
             out, N_user, bufA, bufB, deg, dinv, stream);
    run_type(x_item, ei_item, E_item, W1_item, b1_item, W2_item, b2_item, Wl_item, bl_item,
             out + (size_t)2 * N_user, N_item, bufA, bufB, deg, dinv, stream);
}

// Round 2
// 1035.408 us; speedup vs baseline: 5.7445x; 5.7445x over previous
//
#include <hip/hip_runtime.h>

#define CDIV(a,b) (((a)+(b)-1)/(b))

// ---------------- degree / dinv ----------------
__global__ __launch_bounds__(256) void hg_deg_count(const int* __restrict__ dst, int* __restrict__ deg, int E){
    int e = blockIdx.x*256 + threadIdx.x;
    if (e < E) atomicAdd(&deg[dst[e]], 1);
}

__global__ __launch_bounds__(256) void hg_dinv(const int* __restrict__ deg, float* __restrict__ dinv, int N){
    int v = blockIdx.x*256 + threadIdx.x;
    if (v < N) dinv[v] = rsqrtf((float)(deg[v] + 1));   // +1 self-loop; always > 0
}

// ---------------- exclusive scan of deg -> rowptr (3 kernels) ----------------
// scan1: each block scans 1024 elements (256 threads x 4), writes block total to bsum
__global__ __launch_bounds__(256) void hg_scan1(const int* __restrict__ deg, int* __restrict__ rowptr,
                                                int* __restrict__ bsum, int N){
    __shared__ int sh[256];
    const int t = threadIdx.x;
    const int base = blockIdx.x*1024 + t*4;
    int v0=0,v1=0,v2=0,v3=0;
    if (base+0 < N) v0 = deg[base+0];
    if (base+1 < N) v1 = deg[base+1];
    if (base+2 < N) v2 = deg[base+2];
    if (base+3 < N) v3 = deg[base+3];
    const int s = v0+v1+v2+v3;
    sh[t] = s;
    __syncthreads();
    for (int off = 1; off < 256; off <<= 1){
        int x = 0;
        if (t >= off) x = sh[t-off];
        __syncthreads();
        if (t >= off) sh[t] += x;
        __syncthreads();
    }
    const int excl = sh[t] - s;
    if (t == 255) bsum[blockIdx.x] = sh[255];
    if (base+0 < N) rowptr[base+0] = excl;
    if (base+1 < N) rowptr[base+1] = excl + v0;
    if (base+2 < N) rowptr[base+2] = excl + v0+v1;
    if (base+3 < N) rowptr[base+3] = excl + v0+v1+v2;
}

__global__ void hg_scan2(int* __restrict__ bsum, int nb){
    if (threadIdx.x == 0 && blockIdx.x == 0){
        int acc = 0;
        for (int i = 0; i < nb; ++i){ int v = bsum[i]; bsum[i] = acc; acc += v; }
    }
}

__global__ __launch_bounds__(256) void hg_scan3(int* __restrict__ rowptr, const int* __restrict__ bsum,
                                                int N, int E){
    int i = blockIdx.x*256 + threadIdx.x;
    if (i < N) rowptr[i] += bsum[i >> 10];
    if (i == 0) rowptr[N] = E;
}

// ---------------- CSR edge placement (counting sort by dst) ----------------
__global__ __launch_bounds__(256) void hg_place(const int* __restrict__ src, const int* __restrict__ dst,
                                                int* __restrict__ cursor, int* __restrict__ csr_src, int E){
    int e = blockIdx.x*256 + threadIdx.x;
    if (e < E){
        int d = dst[e];
        int p = atomicAdd(&cursor[d], 1);
        csr_src[p] = src[e];
    }
}

// ---------------- fused GEMM: G[v][j] = (X[v,:] @ W[:,j]) * dinv[v] ----------------
template<int K>
__global__ __launch_bounds__(256) void hg_gemm_scaled(const float* __restrict__ X, const float* __restrict__ W,
                                                      const float* __restrict__ dinv, float* __restrict__ G, int N){
    __shared__ float Wl[K*64];
    for (int i = threadIdx.x; i < K*16; i += 256)
        ((float4*)Wl)[i] = ((const float4*)W)[i];
    __syncthreads();
    const int col  = threadIdx.x & 63;
    const int grp  = threadIdx.x >> 6;
    const int row0 = blockIdx.x * 16 + grp * 4;
    if (row0 >= N) return;
    float a0=0.f, a1=0.f, a2=0.f, a3=0.f;
    const float* x0 = X + (size_t)row0 * K;
    if (row0 + 3 < N) {
        #pragma unroll 4
        for (int k = 0; k < K; k += 4) {
            const float4 xa = *(const float4*)(x0 + 0*(size_t)K + k);
            const float4 xb = *(const float4*)(x0 + 1*(size_t)K + k);
            const float4 xc = *(const float4*)(x0 + 2*(size_t)K + k);
            const float4 xd = *(const float4*)(x0 + 3*(size_t)K + k);
            const float w0 = Wl[(k+0)*64 + col];
            const float w1 = Wl[(k+1)*64 + col];
            const float w2 = Wl[(k+2)*64 + col];
            const float w3 = Wl[(k+3)*64 + col];
            a0 = fmaf(xa.w,w3, fmaf(xa.z,w2, fmaf(xa.y,w1, fmaf(xa.x,w0, a0))));
            a1 = fmaf(xb.w,w3, fmaf(xb.z,w2, fmaf(xb.y,w1, fmaf(xb.x,w0, a1))));
            a2 = fmaf(xc.w,w3, fmaf(xc.z,w2, fmaf(xc.y,w1, fmaf(xc.x,w0, a2))));
            a3 = fmaf(xd.w,w3, fmaf(xd.z,w2, fmaf(xd.y,w1, fmaf(xd.x,w0, a3))));
        }
        G[(size_t)(row0+0)*64 + col] = a0 * dinv[row0+0];
        G[(size_t)(row0+1)*64 + col] = a1 * dinv[row0+1];
        G[(size_t)(row0+2)*64 + col] = a2 * dinv[row0+2];
        G[(size_t)(row0+3)*64 + col] = a3 * dinv[row0+3];
    } else {
        for (int r = 0; r < 4; ++r) {
            int row = row0 + r;
            if (row >= N) break;
            float acc = 0.f;
            const float* xr = X + (size_t)row * K;
            for (int k = 0; k < K; ++k) acc = fmaf(xr[k], Wl[k*64 + col], acc);
            G[(size_t)row*64 + col] = acc * dinv[row];
        }
    }
}

// ---------------- gather-aggregate + fused epilogue ----------------
// one wave per dst node; lane = feature col; out = relu((sum_in g[s] + g[v]) * dinv[v] + b)
__global__ __launch_bounds__(256) void hg_aggregate(const float* __restrict__ g, const int* __restrict__ csr_src,
                                                    const int* __restrict__ rowptr, const float* __restrict__ dinv,
                                                    const float* __restrict__ b, float* __restrict__ outp, int N){
    const int wid  = (blockIdx.x*256 + threadIdx.x) >> 6;
    const int lane = threadIdx.x & 63;
    if (wid >= N) return;
    const int beg = rowptr[wid];
    const int end = rowptr[wid+1];
    float acc = g[(size_t)wid*64 + lane];            // self-loop term
    float a0 = 0.f, a1 = 0.f, a2 = 0.f, a3 = 0.f;
    int i = beg;
    for (; i + 4 <= end; i += 4){
        const int s0 = csr_src[i+0];
        const int s1 = csr_src[i+1];
        const int s2 = csr_src[i+2];
        const int s3 = csr_src[i+3];
        a0 += g[(size_t)s0*64 + lane];
        a1 += g[(size_t)s1*64 + lane];
        a2 += g[(size_t)s2*64 + lane];
        a3 += g[(size_t)s3*64 + lane];
    }
    for (; i < end; ++i)
        a0 += g[(size_t)csr_src[i]*64 + lane];
    acc += (a0 + a1) + (a2 + a3);
    outp[(size_t)wid*64 + lane] = fmaxf(fmaf(acc, dinv[wid], b[lane]), 0.f);
}

// ---------------- head: out[v][0:2] = H[v,:] @ Wl + bl ----------------
__global__ __launch_bounds__(256) void hg_head(const float* __restrict__ H, const float* __restrict__ Wl,
                                               const float* __restrict__ bl, float* __restrict__ outp, int N){
    int v = blockIdx.x*256 + threadIdx.x;
    if (v >= N) return;
    const float* h = H + (size_t)v*64;
    float a0 = bl[0], a1 = bl[1];
    #pragma unroll
    for (int k4 = 0; k4 < 16; ++k4) {
        const float4 x = *(const float4*)(h + k4*4);
        const float4 wA = *(const float4*)(Wl + k4*8 + 0);
        const float4 wB = *(const float4*)(Wl + k4*8 + 4);
        a0 = fmaf(x.x, wA.x, a0); a1 = fmaf(x.x, wA.y, a1);
        a0 = fmaf(x.y, wA.z, a0); a1 = fmaf(x.y, wA.w, a1);
        a0 = fmaf(x.z, wB.x, a0); a1 = fmaf(x.z, wB.y, a1);
        a0 = fmaf(x.w, wB.z, a0); a1 = fmaf(x.w, wB.w, a1);
    }
    float2 r; r.x = a0; r.y = a1;
    *(float2*)(outp + (size_t)v*2) = r;
}

// ---------------- orchestration ----------------
static void run_type(const float* x, const int* ei, int E,
                     const float* W1, const float* b1,
                     const float* W2, const float* b2,
                     const float* Wl, const float* bl,
                     float* out, int N,
                     float* bufA, float* bufB, int* deg, float* dinv,
                     int* rowptr, int* cursor, int* bsum, int* csr_src,
                     hipStream_t stream){
    const int* src = ei;
    const int* dst = ei + E;

    // degree + dinv
    hipMemsetAsync(deg, 0, (size_t)N * sizeof(int), stream);
    hg_deg_count<<<CDIV(E,256), 256, 0, stream>>>(dst, deg, E);
    hg_dinv<<<CDIV(N,256), 256, 0, stream>>>(deg, dinv, N);

    // CSR build (reused by both layers)
    const int nb = CDIV(N, 1024);
    hg_scan1<<<nb, 256, 0, stream>>>(deg, rowptr, bsum, N);
    hg_scan2<<<1, 64, 0, stream>>>(bsum, nb);
    hg_scan3<<<CDIV(N,256), 256, 0, stream>>>(rowptr, bsum, N, E);
    hipMemcpyAsync(cursor, rowptr, (size_t)N * sizeof(int), hipMemcpyDeviceToDevice, stream);
    hg_place<<<CDIV(E,256), 256, 0, stream>>>(src, dst, cursor, csr_src, E);

    // layer 1
    hg_gemm_scaled<128><<<CDIV(N,16), 256, 0, stream>>>(x, W1, dinv, bufA, N);
    hg_aggregate<<<CDIV(N,4), 256, 0, stream>>>(bufA, csr_src, rowptr, dinv, b1, bufB, N);

    // layer 2
    hg_gemm_scaled<64><<<CDIV(N,16), 256, 0, stream>>>(bufB, W2, dinv, bufA, N);
    hg_aggregate<<<CDIV(N,4), 256, 0, stream>>>(bufA, csr_src, rowptr, dinv, b2, bufB, N);

    // head
    hg_head<<<CDIV(N,256), 256, 0, stream>>>(bufB, Wl, bl, out, N);
}

extern "C" void kernel_launch(void* const* d_in, const int* in_sizes, int n_in,
                              void* d_out, int out_size, void* d_ws, size_t ws_size,
                              hipStream_t stream) {
    const float* x_user = (const float*)d_in[0];
    const float* x_item = (const float*)d_in[1];
    const int*  ei_user = (const int*)d_in[2];
    const int*  ei_item = (const int*)d_in[3];
    const float* W1_user = (const float*)d_in[4];
    const float* b1_user = (const float*)d_in[5];
    const float* W1_item = (const float*)d_in[6];
    const float* b1_item = (const float*)d_in[7];
    const float* W2_user = (const float*)d_in[8];
    const float* b2_user = (const float*)d_in[9];
    const float* W2_item = (const float*)d_in[10];
    const float* b2_item = (const float*)d_in[11];
    const float* Wl_user = (const float*)d_in[12];
    const float* bl_user = (const float*)d_in[13];
    const float* Wl_item = (const float*)d_in[14];
    const float* bl_item = (const float*)d_in[15];

    const int N_user = in_sizes[0] / 128;
    const int N_item = in_sizes[1] / 128;
    const int E_user = in_sizes[2] / 2;
    const int E_item = in_sizes[3] / 2;
    const int NMAX = (N_user > N_item) ? N_user : N_item;
    const int EMAX = (E_user > E_item) ? E_user : E_item;

    char* w = (char*)d_ws;
    float* bufA   = (float*)w;  w += (size_t)NMAX * 64 * sizeof(float);
    float* bufB   = (float*)w;  w += (size_t)NMAX * 64 * sizeof(float);
    int*   deg    = (int*)w;    w += (size_t)NMAX * sizeof(int);
    float* dinv   = (float*)w;  w += (size_t)NMAX * sizeof(float);
    int*   rowptr = (int*)w;    w += ((size_t)NMAX + 1) * sizeof(int);
    int*   cursor = (int*)w;    w += (size_t)NMAX * sizeof(int);
    int*   bsum   = (int*)w;    w += (size_t)CDIV(NMAX,1024) * sizeof(int);
    int*   csr_src= (int*)w;    w += (size_t)EMAX * sizeof(int);

    float* out = (float*)d_out;

    run_type(x_user, ei_user, E_user, W1_user, b1_user, W2_user, b2_user, Wl_user, bl_user,
             out, N_user, bufA, bufB, deg, dinv, rowptr, cursor, bsum, csr_src, stream);
    run_type(x_item, ei_item, E_item, W1_item, b1_item, W2_item, b2_item, Wl_item, bl_item,
             out + (size_t)2 * N_user, N_item, bufA, bufB, deg, dinv, rowptr, cursor, bsum, csr_src, stream);
}